// Round 5
// baseline (192.154 us; speedup 1.0000x reference)
//
#include <hip/hip_runtime.h>
#include <stdint.h>

typedef __attribute__((ext_vector_type(8))) _Float16 half8;
typedef __attribute__((ext_vector_type(8))) unsigned short ushort8;
typedef __attribute__((ext_vector_type(4))) float f32x4;
typedef unsigned short u16;

#define AS1C(p) ((const __attribute__((address_space(1))) void*)(p))
#define AS3(p)  ((__attribute__((address_space(3))) void*)(p))

__device__ __forceinline__ f32x4 mfma16(half8 a, half8 b, f32x4 c) {
  return __builtin_amdgcn_mfma_f32_16x16x32_f16(a, b, c, 0, 0, 0);
}
__device__ __forceinline__ u16 f2h(float f) {
  return __builtin_bit_cast(u16, (_Float16)f);
}
__device__ __forceinline__ float fexp2(float x) {
  return __builtin_amdgcn_exp2f(x);
}
__device__ __forceinline__ unsigned int pk2h(float a, float b) {
  return __builtin_bit_cast(unsigned int, __builtin_amdgcn_cvt_pkrtz(a, b));
}

// ---------------- convert / pack fp32 -> fp16 ----------------
__global__ __launch_bounds__(256) void k_convert(
    const float* __restrict__ x, const float* __restrict__ wq,
    const float* __restrict__ wk, const float* __restrict__ wv,
    const float* __restrict__ wo,
    u16* __restrict__ xb, u16* __restrict__ wqkvb, u16* __restrict__ wob) {
  size_t t = (size_t)blockIdx.x * 256 + threadIdx.x;
  size_t e = t * 8;
  const float* src;
  u16* dst;
  if (e < 4194304u)      { src = x  + e;            dst = xb    + e; }
  else if (e < 5242880u) { src = wq + (e-4194304u); dst = wqkvb + (e-4194304u); }
  else if (e < 6291456u) { src = wk + (e-5242880u); dst = wqkvb + (e-4194304u); }
  else if (e < 7340032u) { src = wv + (e-6291456u); dst = wqkvb + (e-4194304u); }
  else                   { src = wo + (e-7340032u); dst = wob   + (e-7340032u); }
  float4 a = *(const float4*)src;
  float4 b = *(const float4*)(src + 4);
  ushort8 o;
  o[0]=f2h(a.x); o[1]=f2h(a.y); o[2]=f2h(a.z); o[3]=f2h(a.w);
  o[4]=f2h(b.x); o[5]=f2h(b.y); o[6]=f2h(b.z); o[7]=f2h(b.w);
  *(ushort8*)dst = o;
}

// ---------------- shared 128x128x(K=1024) GEMM core, prefetch-dbuf ----------
__device__ __forceinline__ void gemm_core(
    const u16* __restrict__ Ag, const u16* __restrict__ Bg,
    int row0, int col0, char* lAc, char* lBc, f32x4 acc[4][4]) {
  const int tid = threadIdx.x;
  const int w = tid >> 6, lane = tid & 63;
  const int wm = (w >> 1) * 64, wn = (w & 1) * 64;
  const int l15 = lane & 15, l4 = lane >> 4;
#pragma unroll
  for (int i = 0; i < 4; ++i)
#pragma unroll
    for (int j = 0; j < 4; ++j) acc[i][j] = (f32x4){0.f, 0.f, 0.f, 0.f};

  const int lrow = lane >> 2;
  const int lcb  = (lane & 3) << 4;
  const char* Abase = (const char*)Ag + (size_t)row0 * 2048;
  const char* Bbase = (const char*)Bg + (size_t)col0 * 2048;

  auto stage = [&](int buf, int kt) {
#pragma unroll
    for (int i = 0; i < 2; ++i) {
      int c = w + 4 * i;
      int r = c * 16 + lrow;
      __builtin_amdgcn_global_load_lds(AS1C(Abase + (size_t)r * 2048 + kt * 64 + lcb),
                                       AS3(lAc + buf * 8192 + c * 1024), 16, 0, 0);
      __builtin_amdgcn_global_load_lds(AS1C(Bbase + (size_t)r * 2048 + kt * 64 + lcb),
                                       AS3(lBc + buf * 8192 + c * 1024), 16, 0, 0);
    }
  };

  stage(0, 0);
  __syncthreads();
  int cur = 0;
  for (int kt = 0; kt < 32; ++kt) {
    if (kt < 31) stage(cur ^ 1, kt + 1);
    const char* A = lAc + cur * 8192;
    const char* B = lBc + cur * 8192;
    half8 af[4], bf[4];
#pragma unroll
    for (int mi = 0; mi < 4; ++mi)
      af[mi] = *(const half8*)(A + (wm + mi * 16 + l15) * 64 + (l4 << 4));
#pragma unroll
    for (int ni = 0; ni < 4; ++ni)
      bf[ni] = *(const half8*)(B + (wn + ni * 16 + l15) * 64 + (l4 << 4));
#pragma unroll
    for (int mi = 0; mi < 4; ++mi)
#pragma unroll
      for (int ni = 0; ni < 4; ++ni)
        acc[mi][ni] = mfma16(af[mi], bf[ni], acc[mi][ni]);
    __syncthreads();
    cur ^= 1;
  }
}

// ---------------- QKV GEMM ----------------
__global__ __launch_bounds__(256) void k_gemm_qkv(
    const u16* __restrict__ xb, const u16* __restrict__ wqkvb,
    u16* __restrict__ qk, u16* __restrict__ vt) {
  __shared__ u16 lA[2 * 4096];
  __shared__ u16 lB[2 * 4096];
  f32x4 acc[4][4];
  const int row0 = blockIdx.y * 128, col0 = blockIdx.x * 128;
  gemm_core(xb, wqkvb, row0, col0, (char*)lA, (char*)lB, acc);

  const int w = threadIdx.x >> 6, lane = threadIdx.x & 63;
  const int l15 = lane & 15, l4 = lane >> 4;
  const int rbase = row0 + (w >> 1) * 64 + (l4 << 2);
  const int cbase = col0 + (w & 1) * 64 + l15;
  const bool isQ = (col0 < 1024);
  const bool isV = (col0 >= 2048);
#pragma unroll
  for (int mi = 0; mi < 4; ++mi) {
#pragma unroll
    for (int ni = 0; ni < 4; ++ni) {
      const int col = cbase + ni * 16;
      if (!isV) {
#pragma unroll
        for (int r = 0; r < 4; ++r) {
          int row = rbase + mi * 16 + r;
          float v = acc[mi][ni][r];
          if (isQ) v *= 0.18033688f;   // 0.125 * log2(e)
          qk[(size_t)row * 2048 + col] = f2h(v);
        }
      } else {
        const int jj = col - 2048;
        const int h = jj >> 6, d = jj & 63;
        const int row = rbase + mi * 16;
        const int b = row >> 11, n = row & 2047;
        u16 pk[4];
#pragma unroll
        for (int r = 0; r < 4; ++r) pk[r] = f2h(acc[mi][ni][r]);
        *(uint2*)&vt[(size_t)(((b << 4) + h) * 64 + d) * 2048 + n] = *(uint2*)pk;
      }
    }
  }
}

// ---------------- flash attention v3: barrier-free, K/V from L2 ----------
// 2 independent waves x 32 q-rows. No LDS staging, no __syncthreads.
// K/V fragments read straight from global (per-XCD L2-resident); both waves
// read identical addresses -> L1 halves L2 traffic. P round-trip in
// per-wave-private LDS (lgkmcnt only). 2-deep K ping-pong pipeline.
__global__ __launch_bounds__(128, 2) void k_attn(
    const u16* __restrict__ qk, const u16* __restrict__ vt, u16* __restrict__ ao) {
  __shared__ u16 Pl[2][2048];   // per wave: 2 subtiles x 16q x 64k fp16
  const int lid = blockIdx.x;
  const int xcd = lid & 7, sub = lid >> 3;
  const int bh = (xcd << 2) + (sub >> 5);
  const int qt = sub & 31;
  const int b = bh >> 4, h = bh & 15;
  const int w = threadIdx.x >> 6, lane = threadIdx.x & 63;
  const int l15 = lane & 15, l4 = lane >> 4;
  const int pswz = (l15 & 7) << 4;

  // Q fragments: q = qt*64 + w*32 + si*16 + l15, k = l4*8+j (+32)
  half8 qf[2][2];
#pragma unroll
  for (int si = 0; si < 2; ++si) {
    const int qrow = (b << 11) + (qt << 6) + (w << 5) + (si << 4) + l15;
#pragma unroll
    for (int kk = 0; kk < 2; ++kk)
      qf[si][kk] = *(const half8*)(qk + (size_t)qrow * 2048 + h * 64 + kk * 32 + (l4 << 3));
  }

  half8 vone;
#pragma unroll
  for (int j = 0; j < 8; ++j) vone[j] = (_Float16)1.0f;

  // global fragment bases
  const char* Kb = (const char*)qk + (size_t)(b << 11) * 4096 + 2048 + h * 128;
  const char* Vb = (const char*)vt + (size_t)(bh * 64) * 4096;
  char* Pwc = (char*)&Pl[w][0];

  auto loadK = [&](half8 (&kf)[4][2], int kt) {
#pragma unroll
    for (int nt = 0; nt < 4; ++nt)
#pragma unroll
      for (int kk = 0; kk < 2; ++kk)
        kf[nt][kk] = *(const half8*)(Kb + (size_t)(kt * 64 + nt * 16 + l15) * 4096 +
                                     kk * 64 + (l4 << 4));
  };
  auto loadV = [&](half8 (&vf)[4][2], int kt) {
#pragma unroll
    for (int nt = 0; nt < 4; ++nt)
#pragma unroll
      for (int kk = 0; kk < 2; ++kk)
        vf[nt][kk] = *(const half8*)(Vb + (size_t)(nt * 16 + l15) * 4096 +
                                     kt * 128 + kk * 64 + (l4 << 4));
  };

  float m_run[2] = {-1e30f, -1e30f};
  f32x4 acc_o[2][4];
  f32x4 acc_l[2];
#pragma unroll
  for (int si = 0; si < 2; ++si) {
    acc_l[si] = (f32x4){0.f, 0.f, 0.f, 0.f};
#pragma unroll
    for (int nt = 0; nt < 4; ++nt) acc_o[si][nt] = (f32x4){0.f, 0.f, 0.f, 0.f};
  }

  // S^T = mfma(K, Q): lane holds q = l15's scores for keys nt*16 + l4*4 + r
  auto qkstep = [&](half8 (&kf)[4][2], f32x4 (&s)[2][4]) {
    __builtin_amdgcn_s_setprio(1);
#pragma unroll
    for (int si = 0; si < 2; ++si)
#pragma unroll
      for (int nt = 0; nt < 4; ++nt) {
        f32x4 z = (f32x4){0.f, 0.f, 0.f, 0.f};
        z = mfma16(kf[nt][0], qf[si][0], z);
        s[si][nt] = mfma16(kf[nt][1], qf[si][1], z);
      }
    __builtin_amdgcn_s_setprio(0);
  };

  auto smpv = [&](f32x4 (&s)[2][4], half8 (&vf)[4][2]) {
#pragma unroll
    for (int si = 0; si < 2; ++si) {
      // balanced max tree (max3-fusable)
      float t0 = fmaxf(fmaxf(s[si][0][0], s[si][0][1]), s[si][0][2]);
      float t1 = fmaxf(fmaxf(s[si][0][3], s[si][1][0]), s[si][1][1]);
      float t2 = fmaxf(fmaxf(s[si][1][2], s[si][1][3]), s[si][2][0]);
      float t3 = fmaxf(fmaxf(s[si][2][1], s[si][2][2]), s[si][2][3]);
      float t4 = fmaxf(fmaxf(s[si][3][0], s[si][3][1]), s[si][3][2]);
      float tm = fmaxf(fmaxf(fmaxf(t0, t1), fmaxf(t2, t3)),
                       fmaxf(t4, s[si][3][3]));

      // defer-max: per-lane partial max is a sound conservative test
      const bool skip = __all(tm - m_run[si] <= 8.f);
      float mnew = m_run[si];
      if (!skip) {
        tm = fmaxf(tm, __shfl_xor(tm, 16));
        tm = fmaxf(tm, __shfl_xor(tm, 32));
        mnew = fmaxf(m_run[si], tm);
        float alpha = fexp2(m_run[si] - mnew);
        m_run[si] = mnew;
#pragma unroll
        for (int r = 0; r < 4; ++r) {
          float av = __shfl(alpha, (l4 << 2) + r);
#pragma unroll
          for (int nt = 0; nt < 4; ++nt) acc_o[si][nt][r] *= av;
          acc_l[si][r] *= av;
        }
      }

      // P = exp2(s - m) -> fp16, one b64 store per nt
#pragma unroll
      for (int nt = 0; nt < 4; ++nt) {
        float p0 = fexp2(s[si][nt][0] - mnew);
        float p1 = fexp2(s[si][nt][1] - mnew);
        float p2 = fexp2(s[si][nt][2] - mnew);
        float p3 = fexp2(s[si][nt][3] - mnew);
        uint2 pk;
        pk.x = pk2h(p0, p1);
        pk.y = pk2h(p2, p3);
        *(uint2*)(Pwc + si * 2048 + ((l15 * 128 + nt * 32 + l4 * 8) ^ pswz)) = pk;
      }
    }

    half8 pa[2][2];
#pragma unroll
    for (int si = 0; si < 2; ++si) {
      pa[si][0] = *(const half8*)(Pwc + si * 2048 + ((l15 * 128 + 0 + (l4 << 4)) ^ pswz));
      pa[si][1] = *(const half8*)(Pwc + si * 2048 + ((l15 * 128 + 64 + (l4 << 4)) ^ pswz));
    }
    __builtin_amdgcn_s_setprio(1);
#pragma unroll
    for (int nt = 0; nt < 4; ++nt) {
#pragma unroll
      for (int si = 0; si < 2; ++si) {
        acc_o[si][nt] = mfma16(pa[si][0], vf[nt][0], acc_o[si][nt]);
        acc_o[si][nt] = mfma16(pa[si][1], vf[nt][1], acc_o[si][nt]);
      }
    }
#pragma unroll
    for (int si = 0; si < 2; ++si) {
      acc_l[si] = mfma16(pa[si][0], vone, acc_l[si]);
      acc_l[si] = mfma16(pa[si][1], vone, acc_l[si]);
    }
    __builtin_amdgcn_s_setprio(0);
  };

  half8 kfA[4][2], kfB[4][2], vf[4][2];
  f32x4 s[2][4];
  loadK(kfA, 0);
  for (int kt = 0; kt < 32; kt += 2) {
    loadV(vf, kt);
    qkstep(kfA, s);
    loadK(kfB, kt + 1);
    smpv(s, vf);
    loadV(vf, kt + 1);
    qkstep(kfB, s);
    if (kt + 2 < 32) loadK(kfA, kt + 2);
    smpv(s, vf);
  }

  // epilogue: O[q][d], q = l4*4+r (same lane as acc_l!), d = nt*16+l15
#pragma unroll
  for (int si = 0; si < 2; ++si) {
    const size_t obase =
        ((size_t)(b << 11) + (qt << 6) + (w << 5) + (si << 4)) * 1024 + h * 64;
#pragma unroll
    for (int r = 0; r < 4; ++r) {
      float inv = __builtin_amdgcn_rcpf(acc_l[si][r]);
      const int q = (l4 << 2) + r;
#pragma unroll
      for (int nt = 0; nt < 4; ++nt)
        ao[obase + (size_t)q * 1024 + nt * 16 + l15] = f2h(acc_o[si][nt][r] * inv);
    }
  }
}

// ---------------- output projection + bias (fp32 out) ----------------
__global__ __launch_bounds__(256) void k_gemm_proj(
    const u16* __restrict__ aob, const u16* __restrict__ wob,
    const float* __restrict__ bo, float* __restrict__ out) {
  __shared__ u16 lA[2 * 4096];
  __shared__ u16 lB[2 * 4096];
  f32x4 acc[4][4];
  const int row0 = blockIdx.y * 128, col0 = blockIdx.x * 128;
  gemm_core(aob, wob, row0, col0, (char*)lA, (char*)lB, acc);

  const int w = threadIdx.x >> 6, lane = threadIdx.x & 63;
  const int l15 = lane & 15, l4 = lane >> 4;
  const int rbase = row0 + (w >> 1) * 64 + (l4 << 2);
  const int cbase = col0 + (w & 1) * 64 + l15;
#pragma unroll
  for (int mi = 0; mi < 4; ++mi) {
#pragma unroll
    for (int ni = 0; ni < 4; ++ni) {
      const int col = cbase + ni * 16;
      const float bb = bo[col];
#pragma unroll
      for (int r = 0; r < 4; ++r) {
        const int row = rbase + mi * 16 + r;
        out[(size_t)row * 1024 + col] = acc[mi][ni][r] + bb;
      }
    }
  }
}

extern "C" void kernel_launch(void* const* d_in, const int* in_sizes, int n_in,
                              void* d_out, int out_size, void* d_ws, size_t ws_size,
                              hipStream_t stream) {
  const float* x  = (const float*)d_in[0];
  const float* wq = (const float*)d_in[1];
  const float* wk = (const float*)d_in[2];
  const float* wv = (const float*)d_in[3];
  const float* wo = (const float*)d_in[4];
  const float* bo = (const float*)d_in[5];
  float* out = (float*)d_out;

  char* ws = (char*)d_ws;
  u16* xb    = (u16*)(ws);                 // [4096][1024] fp16
  u16* wqkvb = (u16*)(ws + 8388608);       // [3072][1024]
  u16* wob   = (u16*)(ws + 14680064);      // [1024][1024]
  u16* qkb   = (u16*)(ws + 16777216);      // [4096][2048]  (Q | K)
  u16* vtb   = (u16*)(ws + 33554432);      // [32][64][2048] V^T per head
  u16* aob   = (u16*)(ws + 41943040);      // [4096][1024]

  k_convert<<<dim3(4096), dim3(256), 0, stream>>>(x, wq, wk, wv, wo, xb, wqkvb, wob);
  k_gemm_qkv<<<dim3(24, 32), dim3(256), 0, stream>>>(xb, wqkvb, qkb, vtb);
  k_attn<<<dim3(1024), dim3(128), 0, stream>>>(qkb, vtb, aob);
  k_gemm_proj<<<dim3(8, 32), dim3(256), 0, stream>>>(aob, wob, bo, out);
}

// Round 6
// 136.480 us; speedup vs baseline: 1.4079x; 1.4079x over previous
//
#include <hip/hip_runtime.h>
#include <stdint.h>

typedef __attribute__((ext_vector_type(8))) _Float16 half8;
typedef __attribute__((ext_vector_type(8))) unsigned short ushort8;
typedef __attribute__((ext_vector_type(4))) float f32x4;
typedef unsigned short u16;

#define AS1C(p) ((const __attribute__((address_space(1))) void*)(p))
#define AS3(p)  ((__attribute__((address_space(3))) void*)(p))

__device__ __forceinline__ f32x4 mfma16(half8 a, half8 b, f32x4 c) {
  return __builtin_amdgcn_mfma_f32_16x16x32_f16(a, b, c, 0, 0, 0);
}
__device__ __forceinline__ u16 f2h(float f) {
  return __builtin_bit_cast(u16, (_Float16)f);
}
__device__ __forceinline__ float fexp2(float x) {
  return __builtin_amdgcn_exp2f(x);
}
__device__ __forceinline__ unsigned int pk2h(float a, float b) {
  return __builtin_bit_cast(unsigned int, __builtin_amdgcn_cvt_pkrtz(a, b));
}

// ---------------- convert / pack fp32 -> fp16 ----------------
__global__ __launch_bounds__(256) void k_convert(
    const float* __restrict__ x, const float* __restrict__ wq,
    const float* __restrict__ wk, const float* __restrict__ wv,
    const float* __restrict__ wo,
    u16* __restrict__ xb, u16* __restrict__ wqkvb, u16* __restrict__ wob) {
  size_t t = (size_t)blockIdx.x * 256 + threadIdx.x;
  size_t e = t * 8;
  const float* src;
  u16* dst;
  if (e < 4194304u)      { src = x  + e;            dst = xb    + e; }
  else if (e < 5242880u) { src = wq + (e-4194304u); dst = wqkvb + (e-4194304u); }
  else if (e < 6291456u) { src = wk + (e-5242880u); dst = wqkvb + (e-4194304u); }
  else if (e < 7340032u) { src = wv + (e-6291456u); dst = wqkvb + (e-4194304u); }
  else                   { src = wo + (e-7340032u); dst = wob   + (e-7340032u); }
  float4 a = *(const float4*)src;
  float4 b = *(const float4*)(src + 4);
  ushort8 o;
  o[0]=f2h(a.x); o[1]=f2h(a.y); o[2]=f2h(a.z); o[3]=f2h(a.w);
  o[4]=f2h(b.x); o[5]=f2h(b.y); o[6]=f2h(b.z); o[7]=f2h(b.w);
  *(ushort8*)dst = o;
}

// ---------------- shared 128x128x(K=1024) GEMM core, prefetch-dbuf ----------
__device__ __forceinline__ void gemm_core(
    const u16* __restrict__ Ag, const u16* __restrict__ Bg,
    int row0, int col0, char* lAc, char* lBc, f32x4 acc[4][4]) {
  const int tid = threadIdx.x;
  const int w = tid >> 6, lane = tid & 63;
  const int wm = (w >> 1) * 64, wn = (w & 1) * 64;
  const int l15 = lane & 15, l4 = lane >> 4;
#pragma unroll
  for (int i = 0; i < 4; ++i)
#pragma unroll
    for (int j = 0; j < 4; ++j) acc[i][j] = (f32x4){0.f, 0.f, 0.f, 0.f};

  const int lrow = lane >> 2;
  const int lcb  = (lane & 3) << 4;
  const char* Abase = (const char*)Ag + (size_t)row0 * 2048;
  const char* Bbase = (const char*)Bg + (size_t)col0 * 2048;

  auto stage = [&](int buf, int kt) {
#pragma unroll
    for (int i = 0; i < 2; ++i) {
      int c = w + 4 * i;
      int r = c * 16 + lrow;
      __builtin_amdgcn_global_load_lds(AS1C(Abase + (size_t)r * 2048 + kt * 64 + lcb),
                                       AS3(lAc + buf * 8192 + c * 1024), 16, 0, 0);
      __builtin_amdgcn_global_load_lds(AS1C(Bbase + (size_t)r * 2048 + kt * 64 + lcb),
                                       AS3(lBc + buf * 8192 + c * 1024), 16, 0, 0);
    }
  };

  stage(0, 0);
  __syncthreads();
  int cur = 0;
  for (int kt = 0; kt < 32; ++kt) {
    if (kt < 31) stage(cur ^ 1, kt + 1);
    const char* A = lAc + cur * 8192;
    const char* B = lBc + cur * 8192;
    half8 af[4], bf[4];
#pragma unroll
    for (int mi = 0; mi < 4; ++mi)
      af[mi] = *(const half8*)(A + (wm + mi * 16 + l15) * 64 + (l4 << 4));
#pragma unroll
    for (int ni = 0; ni < 4; ++ni)
      bf[ni] = *(const half8*)(B + (wn + ni * 16 + l15) * 64 + (l4 << 4));
#pragma unroll
    for (int mi = 0; mi < 4; ++mi)
#pragma unroll
      for (int ni = 0; ni < 4; ++ni)
        acc[mi][ni] = mfma16(af[mi], bf[ni], acc[mi][ni]);
    __syncthreads();
    cur ^= 1;
  }
}

// ---------------- QKV GEMM ----------------
__global__ __launch_bounds__(256) void k_gemm_qkv(
    const u16* __restrict__ xb, const u16* __restrict__ wqkvb,
    u16* __restrict__ qk, u16* __restrict__ vt) {
  __shared__ u16 lA[2 * 4096];
  __shared__ u16 lB[2 * 4096];
  f32x4 acc[4][4];
  const int row0 = blockIdx.y * 128, col0 = blockIdx.x * 128;
  gemm_core(xb, wqkvb, row0, col0, (char*)lA, (char*)lB, acc);

  const int w = threadIdx.x >> 6, lane = threadIdx.x & 63;
  const int l15 = lane & 15, l4 = lane >> 4;
  const int rbase = row0 + (w >> 1) * 64 + (l4 << 2);
  const int cbase = col0 + (w & 1) * 64 + l15;
  const bool isQ = (col0 < 1024);
  const bool isV = (col0 >= 2048);
#pragma unroll
  for (int mi = 0; mi < 4; ++mi) {
#pragma unroll
    for (int ni = 0; ni < 4; ++ni) {
      const int col = cbase + ni * 16;
      if (!isV) {
#pragma unroll
        for (int r = 0; r < 4; ++r) {
          int row = rbase + mi * 16 + r;
          float v = acc[mi][ni][r];
          if (isQ) v *= 0.18033688f;   // 0.125 * log2(e)
          qk[(size_t)row * 2048 + col] = f2h(v);
        }
      } else {
        const int jj = col - 2048;
        const int h = jj >> 6, d = jj & 63;
        const int row = rbase + mi * 16;
        const int b = row >> 11, n = row & 2047;
        u16 pk[4];
#pragma unroll
        for (int r = 0; r < 4; ++r) pk[r] = f2h(acc[mi][ni][r]);
        *(uint2*)&vt[(size_t)(((b << 4) + h) * 64 + d) * 2048 + n] = *(uint2*)pk;
      }
    }
  }
}

// ---------------- flash attention v4: counted-vmcnt, raw barriers ----------
// 2 waves x 32 q-rows (two 16-row subtiles sharing K/V fragments).
// LDS-staged K/V (shared), dbuf, per-iter: stage(t+1) -> vmcnt(8) ->
// s_barrier -> compute(t) -> s_barrier. Prefetch stays in flight across
// the barrier (T3/T4); waves drift inside compute -> T5 setprio pays.
__global__ __launch_bounds__(128) void k_attn(
    const u16* __restrict__ qk, const u16* __restrict__ vt, u16* __restrict__ ao) {
  __shared__ u16 Kl[2][4096];
  __shared__ u16 Vl[2][4096];
  __shared__ u16 Pl[2][2048];   // per wave: 2 subtiles x 16q x 64k fp16
  const int lid = blockIdx.x;
  const int xcd = lid & 7, sub = lid >> 3;
  const int bh = (xcd << 2) + (sub >> 5);
  const int qt = sub & 31;
  const int b = bh >> 4, h = bh & 15;
  const int w = threadIdx.x >> 6, lane = threadIdx.x & 63;
  const int l15 = lane & 15, l4 = lane >> 4;
  const int pswz = (l15 & 7) << 4;

  // Q fragments: q = qt*64 + w*32 + si*16 + l15, k = l4*8+j (+32)
  half8 qf[2][2];
#pragma unroll
  for (int si = 0; si < 2; ++si) {
    const int qrow = (b << 11) + (qt << 6) + (w << 5) + (si << 4) + l15;
#pragma unroll
    for (int kk = 0; kk < 2; ++kk)
      qf[si][kk] = *(const half8*)(qk + (size_t)qrow * 2048 + h * 64 + kk * 32 + (l4 << 3));
  }

  half8 vone;
#pragma unroll
  for (int j = 0; j < 8; ++j) vone[j] = (_Float16)1.0f;

  const int lrow = lane >> 3;         // 0..7
  const int lcb  = (lane & 7) << 4;   // 0..112
  const char* Kbase = (const char*)qk + (size_t)(b << 11) * 4096 + 2048 + h * 128;
  const char* Vbase = (const char*)vt + (size_t)(bh * 64) * 4096;
  char* Pwc = (char*)&Pl[w][0];

  // 8 global_load_lds per wave per stage
  auto stage = [&](int buf, int kt) {
#pragma unroll
    for (int i = 0; i < 4; ++i) {
      int c = (i << 1) + w;                 // chunks 0..7 split over 2 waves
      int rr = c * 8 + lrow;
      int scb = lcb ^ ((rr & 7) << 4);
      __builtin_amdgcn_global_load_lds(AS1C(Kbase + (size_t)(kt * 64 + rr) * 4096 + scb),
                                       AS3((char*)&Kl[buf][0] + c * 1024), 16, 0, 0);
      __builtin_amdgcn_global_load_lds(AS1C(Vbase + (size_t)rr * 4096 + kt * 128 + scb),
                                       AS3((char*)&Vl[buf][0] + c * 1024), 16, 0, 0);
    }
  };

  float m_run[2] = {-1e30f, -1e30f};
  f32x4 acc_o[2][4];
  f32x4 acc_l[2];
#pragma unroll
  for (int si = 0; si < 2; ++si) {
    acc_l[si] = (f32x4){0.f, 0.f, 0.f, 0.f};
#pragma unroll
    for (int nt = 0; nt < 4; ++nt) acc_o[si][nt] = (f32x4){0.f, 0.f, 0.f, 0.f};
  }

  stage(0, 0);
  int cur = 0;
  for (int kt = 0; kt < 32; ++kt) {
    if (kt < 31) {
      stage(cur ^ 1, kt + 1);
      asm volatile("s_waitcnt vmcnt(8)" ::: "memory");   // own prev-stage done
    } else {
      asm volatile("s_waitcnt vmcnt(0)" ::: "memory");
    }
    __builtin_amdgcn_s_barrier();          // all waves' stage(t) complete
    __builtin_amdgcn_sched_barrier(0);
    const char* Klc = (const char*)&Kl[cur][0];
    const char* Vlc = (const char*)&Vl[cur][0];

    // K fragments, read once, shared by both q-subtiles
    half8 kf[4][2];
#pragma unroll
    for (int nt = 0; nt < 4; ++nt) {
      const int key = nt * 16 + l15;
      kf[nt][0] = *(const half8*)(Klc + key * 128 + (((l4 << 4) + 0) ^ pswz));
      kf[nt][1] = *(const half8*)(Klc + key * 128 + (((l4 << 4) + 64) ^ pswz));
    }

    // S^T = mfma(K, Q): lane holds q = l15's scores for keys nt*16 + l4*4 + r
    f32x4 s[2][4];
    __builtin_amdgcn_s_setprio(1);
#pragma unroll
    for (int si = 0; si < 2; ++si)
#pragma unroll
      for (int nt = 0; nt < 4; ++nt) {
        f32x4 z = (f32x4){0.f, 0.f, 0.f, 0.f};
        z = mfma16(kf[nt][0], qf[si][0], z);
        s[si][nt] = mfma16(kf[nt][1], qf[si][1], z);
      }
    __builtin_amdgcn_s_setprio(0);

    // per-subtile softmax
#pragma unroll
    for (int si = 0; si < 2; ++si) {
      float t0 = fmaxf(fmaxf(s[si][0][0], s[si][0][1]), s[si][0][2]);
      float t1 = fmaxf(fmaxf(s[si][0][3], s[si][1][0]), s[si][1][1]);
      float t2 = fmaxf(fmaxf(s[si][1][2], s[si][1][3]), s[si][2][0]);
      float t3 = fmaxf(fmaxf(s[si][2][1], s[si][2][2]), s[si][2][3]);
      float t4 = fmaxf(fmaxf(s[si][3][0], s[si][3][1]), s[si][3][2]);
      float tm = fmaxf(fmaxf(fmaxf(t0, t1), fmaxf(t2, t3)),
                       fmaxf(t4, s[si][3][3]));

      const bool skip = __all(tm - m_run[si] <= 8.f);   // defer-max
      float mnew = m_run[si];
      if (!skip) {
        tm = fmaxf(tm, __shfl_xor(tm, 16));
        tm = fmaxf(tm, __shfl_xor(tm, 32));
        mnew = fmaxf(m_run[si], tm);
        float alpha = fexp2(m_run[si] - mnew);
        m_run[si] = mnew;
#pragma unroll
        for (int r = 0; r < 4; ++r) {
          float av = __shfl(alpha, (l4 << 2) + r);
#pragma unroll
          for (int nt = 0; nt < 4; ++nt) acc_o[si][nt][r] *= av;
          acc_l[si][r] *= av;
        }
      }

      // P = exp2(s - m) -> fp16, one b64 store per nt
#pragma unroll
      for (int nt = 0; nt < 4; ++nt) {
        float p0 = fexp2(s[si][nt][0] - mnew);
        float p1 = fexp2(s[si][nt][1] - mnew);
        float p2 = fexp2(s[si][nt][2] - mnew);
        float p3 = fexp2(s[si][nt][3] - mnew);
        uint2 pk;
        pk.x = pk2h(p0, p1);
        pk.y = pk2h(p2, p3);
        *(uint2*)(Pwc + si * 2048 + ((l15 * 128 + nt * 32 + l4 * 8) ^ pswz)) = pk;
      }
    }

    // PV + l-sum: V fragments read once, shared by both subtiles
    half8 pa[2][2];
#pragma unroll
    for (int si = 0; si < 2; ++si) {
      pa[si][0] = *(const half8*)(Pwc + si * 2048 + ((l15 * 128 + 0 + (l4 << 4)) ^ pswz));
      pa[si][1] = *(const half8*)(Pwc + si * 2048 + ((l15 * 128 + 64 + (l4 << 4)) ^ pswz));
    }
    __builtin_amdgcn_s_setprio(1);
#pragma unroll
    for (int nt = 0; nt < 4; ++nt) {
      const int d = nt * 16 + l15;
      half8 v0 = *(const half8*)(Vlc + d * 128 + (((l4 << 4) + 0) ^ pswz));
      half8 v1 = *(const half8*)(Vlc + d * 128 + (((l4 << 4) + 64) ^ pswz));
#pragma unroll
      for (int si = 0; si < 2; ++si) {
        acc_o[si][nt] = mfma16(pa[si][0], v0, acc_o[si][nt]);
        acc_o[si][nt] = mfma16(pa[si][1], v1, acc_o[si][nt]);
      }
    }
#pragma unroll
    for (int si = 0; si < 2; ++si) {
      acc_l[si] = mfma16(pa[si][0], vone, acc_l[si]);
      acc_l[si] = mfma16(pa[si][1], vone, acc_l[si]);
    }
    __builtin_amdgcn_s_setprio(0);
    __builtin_amdgcn_s_barrier();          // seal reads before next overwrite
    cur ^= 1;
  }

  // epilogue: O[q][d], q = l4*4+r (same lane as acc_l!), d = nt*16+l15
#pragma unroll
  for (int si = 0; si < 2; ++si) {
    const size_t obase =
        ((size_t)(b << 11) + (qt << 6) + (w << 5) + (si << 4)) * 1024 + h * 64;
#pragma unroll
    for (int r = 0; r < 4; ++r) {
      float inv = __builtin_amdgcn_rcpf(acc_l[si][r]);
      const int q = (l4 << 2) + r;
#pragma unroll
      for (int nt = 0; nt < 4; ++nt)
        ao[obase + (size_t)q * 1024 + nt * 16 + l15] = f2h(acc_o[si][nt][r] * inv);
    }
  }
}

// ---------------- output projection + bias (fp32 out) ----------------
__global__ __launch_bounds__(256) void k_gemm_proj(
    const u16* __restrict__ aob, const u16* __restrict__ wob,
    const float* __restrict__ bo, float* __restrict__ out) {
  __shared__ u16 lA[2 * 4096];
  __shared__ u16 lB[2 * 4096];
  f32x4 acc[4][4];
  const int row0 = blockIdx.y * 128, col0 = blockIdx.x * 128;
  gemm_core(aob, wob, row0, col0, (char*)lA, (char*)lB, acc);

  const int w = threadIdx.x >> 6, lane = threadIdx.x & 63;
  const int l15 = lane & 15, l4 = lane >> 4;
  const int rbase = row0 + (w >> 1) * 64 + (l4 << 2);
  const int cbase = col0 + (w & 1) * 64 + l15;
#pragma unroll
  for (int mi = 0; mi < 4; ++mi) {
#pragma unroll
    for (int ni = 0; ni < 4; ++ni) {
      const int col = cbase + ni * 16;
      const float bb = bo[col];
#pragma unroll
      for (int r = 0; r < 4; ++r) {
        const int row = rbase + mi * 16 + r;
        out[(size_t)row * 1024 + col] = acc[mi][ni][r] + bb;
      }
    }
  }
}

extern "C" void kernel_launch(void* const* d_in, const int* in_sizes, int n_in,
                              void* d_out, int out_size, void* d_ws, size_t ws_size,
                              hipStream_t stream) {
  const float* x  = (const float*)d_in[0];
  const float* wq = (const float*)d_in[1];
  const float* wk = (const float*)d_in[2];
  const float* wv = (const float*)d_in[3];
  const float* wo = (const float*)d_in[4];
  const float* bo = (const float*)d_in[5];
  float* out = (float*)d_out;

  char* ws = (char*)d_ws;
  u16* xb    = (u16*)(ws);                 // [4096][1024] fp16
  u16* wqkvb = (u16*)(ws + 8388608);       // [3072][1024]
  u16* wob   = (u16*)(ws + 14680064);      // [1024][1024]
  u16* qkb   = (u16*)(ws + 16777216);      // [4096][2048]  (Q | K)
  u16* vtb   = (u16*)(ws + 33554432);      // [32][64][2048] V^T per head
  u16* aob   = (u16*)(ws + 41943040);      // [4096][1024]

  k_convert<<<dim3(4096), dim3(256), 0, stream>>>(x, wq, wk, wv, wo, xb, wqkvb, wob);
  k_gemm_qkv<<<dim3(24, 32), dim3(256), 0, stream>>>(xb, wqkvb, qkb, vtb);
  k_attn<<<dim3(1024), dim3(128), 0, stream>>>(qkb, vtb, aob);
  k_gemm_proj<<<dim3(8, 32), dim3(256), 0, stream>>>(aob, wob, bo, out);
}